// Round 19
// baseline (282.674 us; speedup 1.0000x reference)
//
#include <hip/hip_runtime.h>
#include <hip/hip_bf16.h>

typedef __attribute__((ext_vector_type(8))) short short8;
typedef __attribute__((ext_vector_type(4))) short short4b;
typedef __attribute__((ext_vector_type(4))) float f32x4;
typedef unsigned short ushort_t;

#define NTOK 262144   // B*D*H*W = 2*32*64*64

__device__ __forceinline__ ushort_t f2bf(float f){
  __hip_bfloat16 h = __float2bfloat16(f);
  return *reinterpret_cast<ushort_t*>(&h);
}
__device__ __forceinline__ float bf2f(ushort_t u){
  union { unsigned int i; float f; } v; v.i = ((unsigned int)u) << 16; return v.f;
}
__device__ __forceinline__ float fast_rcp(float x){
  float r; asm("v_rcp_f32 %0, %1" : "=v"(r) : "v"(x)); return r;
}
// sigmoid-form gelu (err <=0.005 for |x|<~1; our pre-act std ~0.2)
__device__ __forceinline__ float gelu_f(float x){
  float e = __expf(-1.702f * x);
  return x * fast_rcp(1.0f + e);
}
__device__ __forceinline__ void bar_lds(){
  asm volatile("s_waitcnt lgkmcnt(0)" ::: "memory");
  __builtin_amdgcn_s_barrier();
  __builtin_amdgcn_sched_barrier(0);
}
__device__ __forceinline__ void bar_cnt3(){
  asm volatile("s_waitcnt vmcnt(3) lgkmcnt(0)" ::: "memory");
  __builtin_amdgcn_s_barrier();
  __builtin_amdgcn_sched_barrier(0);
}
__device__ __forceinline__ void bar_cnt0(){
  asm volatile("s_waitcnt vmcnt(0) lgkmcnt(0)" ::: "memory");
  __builtin_amdgcn_s_barrier();
  __builtin_amdgcn_sched_barrier(0);
}
__device__ __forceinline__ void gl_lds16(const ushort_t* g, ushort_t* l){
  __builtin_amdgcn_global_load_lds(
      (const __attribute__((address_space(1))) void*)g,
      (__attribute__((address_space(3))) void*)l, 16, 0, 0);
}

// stage a LINEAR 48x96 half-slice, UNIFORM 3 loads/thread (768 units; units
// 576..767 re-read src unit 0, land in never-read LDS pad). Per-wave-uniform branch.
__device__ __forceinline__ void stage_half3(const ushort_t* __restrict__ src,
                                            ushort_t* __restrict__ dst, int tid)
{
  #pragma unroll
  for (int it = 0; it < 3; ++it) {
    int u = tid + it * 256;
    const ushort_t* sp = src + (size_t)((u < 576) ? u : 0) * 8;
    gl_lds16(sp, dst + (size_t)(u & ~63) * 8);
  }
}

// half-slice source for pipeline index hidx (0..23)
__device__ __forceinline__ const ushort_t* stage_src(int hidx,
    const ushort_t* Wqkv, const ushort_t* Wo, const ushort_t* W1t, const ushort_t* W2c)
{
  if (hidx < 6) return Wqkv + (size_t)hidx * 4608;
  if (hidx < 8) return Wo + (size_t)(hidx - 6) * 4608;
  int m = hidx - 8, cc = m >> 2, p = m & 3;
  const ushort_t* base = (p < 2) ? W1t : W2c;
  return base + (size_t)cc * 9216 + (size_t)(p & 1) * 4608;
}

// ---------------- weight prep: fp32 -> bf16; Q-scale folded; W2 chunk-major ----------------
__global__ __launch_bounds__(256) void prep_kernel(
    const float* __restrict__ wq, const float* __restrict__ wk, const float* __restrict__ wv,
    const float* __restrict__ wo, const float* __restrict__ w1, const float* __restrict__ w2,
    const float* __restrict__ bq, const float* __restrict__ bk, const float* __restrict__ bv,
    ushort_t* __restrict__ Wqkv, ushort_t* __restrict__ Wo,
    ushort_t* __restrict__ W1, ushort_t* __restrict__ W2c, float* __restrict__ biasq)
{
  const float qs = 0.20412414523193150818f;   // 1/sqrt(24)
  int i = blockIdx.x * 256 + threadIdx.x;
  if (i < 27648) {                       // Wqkv_t[j][c], j = s*96 + h*24 + d
    int j = i / 96, c = i % 96;
    int s = j / 96, rem = j % 96;
    const float* src = (s == 0) ? wq : (s == 1) ? wk : wv;
    float val = src[c * 96 + rem];
    if (s == 0) val *= qs;
    Wqkv[j * 96 + c] = f2bf(val);
  } else if (i < 36864) {                // Wo_t[c][hd] = wo[hd][c]
    int ii = i - 27648;
    int c = ii / 96, hd = ii % 96;
    Wo[ii] = f2bf(wo[hd * 96 + c]);
  } else if (i < 73728) {                // W1_t[j][c] = w1[c][j]  ([384][96])
    int ii = i - 36864;
    int j = ii / 96, c = ii % 96;
    W1[ii] = f2bf(w1[c * 384 + j]);
  } else if (i < 110592) {               // W2c[cc][j][kk] = w2[(cc*96+kk)][j]
    int ii = i - 73728;
    int cc = ii / 9216, rem = ii % 9216;
    int j = rem / 96, kk = rem % 96;
    W2c[ii] = f2bf(w2[(size_t)(cc * 96 + kk) * 96 + j]);
  } else if (i < 110880) {               // combined qkv bias (fp32), Q part scaled
    int j = i - 110592;
    int s = j / 96, rem = j % 96;
    const float* src = (s == 0) ? bq : (s == 1) ? bk : bv;
    float val = src[rem];
    if (s == 0) val *= qs;
    biasq[j] = val;
  }
}

// ================= MEGA: LN1+QKV+attn+proj+res -> LN2+MLP+res -> out =================
// Block = 1 window (64 tokens), 4 waves. 24-phase weight ping-pong (uniform-3
// stages, counted vmcnt). All token-state after proj is wave-private.
// LDS = 38,912 + 18,432 + 24,576 = 81,920 B -> exactly 2 blocks/CU.
__global__ __launch_bounds__(256, 2) void fat2_kernel(
    const float* __restrict__ x, const float* __restrict__ g, const float* __restrict__ b,
    const ushort_t* __restrict__ Wqkv, const float* __restrict__ biasq,
    const ushort_t* __restrict__ Wo, const float* __restrict__ bo,
    const float* __restrict__ ln2g, const float* __restrict__ ln2b,
    const ushort_t* __restrict__ W1t, const float* __restrict__ b1,
    const ushort_t* __restrict__ W2c, const float* __restrict__ b2,
    float* __restrict__ outp)
{
  __shared__ ushort_t regionA[19456];      // 38,912 B
  __shared__ ushort_t Vt[4][32][72];       // 18,432 B
  __shared__ ushort_t WsH[2][6144];        // 24,576 B ping-pong half-slices
  ushort_t (*hbt)[104]   = reinterpret_cast<ushort_t(*)[104]>(regionA);  // LN1 out
  ushort_t (*QK)[200]    = reinterpret_cast<ushort_t(*)[200]>(regionA);  // aliases hbt (af in regs first)
  ushort_t (*Pb)[64][72] = reinterpret_cast<ushort_t(*)[64][72]>(regionA);
  ushort_t (*O_lds)[104] = reinterpret_cast<ushort_t(*)[104]>(regionA);
  ushort_t* h_ln = regionA;                // [64][104] (same per-wave partition as O_lds)
  ushort_t* mid  = regionA + 6656;         // [64][104]
  ushort_t* x2L  = regionA + 13312;        // [64][96]

  int tid = threadIdx.x;
  int n = blockIdx.x;
  int wq_ = n & 15, hq = (n >> 4) & 15, rest = n >> 8;
  int dq = rest & 7, bb_ = rest >> 3;
  int base = bb_ * 131072 + dq * 16384 + hq * 256 + wq_ * 4;
  #define TOK(s) (base + ((s) >> 4) * 4096 + (((s) >> 2) & 3) * 64 + ((s) & 3))

  stage_half3(Wqkv, WsH[0], tid);          // hidx 0
  stage_half3(Wqkv + 4608, WsH[1], tid);   // hidx 1 (fly under LN1)

  // ---- LN1: thread t -> slot t>>2, quarter t&3 (wave-private rows) ----
  {
    int s = tid >> 2, qr = tid & 3;
    const float* xp = x + (size_t)TOK(s) * 96 + qr * 24;
    f32x4 v[6];
    float sm = 0.f, sq = 0.f;
    #pragma unroll
    for (int i = 0; i < 6; i++) {
      v[i] = *reinterpret_cast<const f32x4*>(xp + i * 4);
      #pragma unroll
      for (int j = 0; j < 4; j++) { sm += v[i][j]; sq += v[i][j] * v[i][j]; }
    }
    sm += __shfl_xor(sm, 1); sq += __shfl_xor(sq, 1);
    sm += __shfl_xor(sm, 2); sq += __shfl_xor(sq, 2);
    float mean = sm * (1.0f / 96.0f);
    float var  = sq * (1.0f / 96.0f) - mean * mean;
    float rstd = rsqrtf(var + 1e-5f);
    #pragma unroll
    for (int i8 = 0; i8 < 3; i8++) {
      short8 pk;
      #pragma unroll
      for (int j = 0; j < 8; j++) {
        int c = qr * 24 + i8 * 8 + j;
        pk[j] = (short)f2bf((v[(i8 * 8 + j) >> 2][(i8 * 8 + j) & 3] - mean) * rstd * g[c] + b[c]);
      }
      *reinterpret_cast<short8*>(&hbt[s][qr * 24 + i8 * 8]) = pk;
    }
  }

  int w = tid >> 6, lane = tid & 63, g16 = lane >> 4, l15 = lane & 15;
  short8 af[3];                            // own-wave LN rows (in-order LDS)
  #pragma unroll
  for (int ks = 0; ks < 3; ks++)
    af[ks] = *reinterpret_cast<const short8*>(&hbt[w * 16 + l15][ks * 32 + g16 * 8]);
  __builtin_amdgcn_sched_barrier(0);

  // ---- QKV: 6 half-slice phases (hidx 0..5) ----
  for (int hidx = 0; hidx < 6; ++hidx) {
    const ushort_t* buf = WsH[hidx & 1];
    bar_cnt3();
    f32x4 acc[3];
    #pragma unroll
    for (int jj = 0; jj < 3; jj++) acc[jj] = (f32x4){0.f, 0.f, 0.f, 0.f};
    __builtin_amdgcn_s_setprio(1);
    #pragma unroll
    for (int jj = 0; jj < 3; jj++)
      #pragma unroll
      for (int ks = 0; ks < 3; ks++) {
        short8 wfr = *reinterpret_cast<const short8*>(&buf[(jj * 16 + l15) * 96 + ks * 32 + g16 * 8]);
        acc[jj] = __builtin_amdgcn_mfma_f32_16x16x32_bf16(wfr, af[ks], acc[jj], 0, 0, 0);
      }
    __builtin_amdgcn_s_setprio(0);
    bar_lds();
    stage_half3(stage_src(hidx + 2, Wqkv, Wo, W1t, W2c), WsH[hidx & 1], tid);
    int grp = hidx >> 1, half = hidx & 1;
    if (grp < 2) {
      #pragma unroll
      for (int jj = 0; jj < 3; jj++) {
        int c0 = grp * 96 + (half * 3 + jj) * 16 + g16 * 4;
        f32x4 bb4 = *reinterpret_cast<const f32x4*>(&biasq[c0]);
        unsigned lo = (unsigned)f2bf(acc[jj][0] + bb4[0]) | ((unsigned)f2bf(acc[jj][1] + bb4[1]) << 16);
        unsigned hi = (unsigned)f2bf(acc[jj][2] + bb4[2]) | ((unsigned)f2bf(acc[jj][3] + bb4[3]) << 16);
        uint2 pk; pk.x = lo; pk.y = hi;
        *reinterpret_cast<uint2*>(&QK[w * 16 + l15][c0]) = pk;
      }
    } else {
      #pragma unroll
      for (int jj = 0; jj < 3; jj++) {
        int c0 = (half * 3 + jj) * 16 + g16 * 4;
        f32x4 bb4 = *reinterpret_cast<const f32x4*>(&biasq[192 + c0]);
        #pragma unroll
        for (int r = 0; r < 4; r++) {
          int vcol = c0 + r;
          int h2 = vcol / 24, d2 = vcol - h2 * 24;
          Vt[h2][d2][w * 16 + l15] = f2bf(acc[jj][r] + bb4[r]);
        }
      }
    }
  }
  bar_lds();                               // QK/Vt visible

  // ---- attention: wave = head ----
  int h = w;
  short8 kf[4], qf[4];
  const short8 z8 = {0, 0, 0, 0, 0, 0, 0, 0};
  #pragma unroll
  for (int i = 0; i < 4; i++) {
    qf[i] = (g16 < 3) ? *(const short8*)&QK[i * 16 + l15][h * 24 + g16 * 8]      : z8;
    kf[i] = (g16 < 3) ? *(const short8*)&QK[i * 16 + l15][96 + h * 24 + g16 * 8] : z8;
  }
  f32x4 st[4][4];
  __builtin_amdgcn_s_setprio(1);
  #pragma unroll
  for (int tm = 0; tm < 4; tm++)
    #pragma unroll
    for (int tn = 0; tn < 4; tn++)
      st[tm][tn] = __builtin_amdgcn_mfma_f32_16x16x32_bf16(kf[tm], qf[tn],
                    (f32x4){0.f, 0.f, 0.f, 0.f}, 0, 0, 0);
  __builtin_amdgcn_s_setprio(0);
  bar_lds();                               // QK reads done (P aliases region)

  #pragma unroll
  for (int tn = 0; tn < 4; tn++) {
    float m = st[0][tn][0];
    #pragma unroll
    for (int tm = 0; tm < 4; tm++)
      #pragma unroll
      for (int r = 0; r < 4; r++) m = fmaxf(m, st[tm][tn][r]);
    m = fmaxf(m, __shfl_xor(m, 16));
    m = fmaxf(m, __shfl_xor(m, 32));
    float sum = 0.f;
    #pragma unroll
    for (int tm = 0; tm < 4; tm++)
      #pragma unroll
      for (int r = 0; r < 4; r++) {
        float e = __expf(st[tm][tn][r] - m);
        st[tm][tn][r] = e;
        sum += e;
      }
    sum += __shfl_xor(sum, 16);
    sum += __shfl_xor(sum, 32);
    float inv = fast_rcp(sum);
    int q = tn * 16 + l15;
    #pragma unroll
    for (int tm = 0; tm < 4; tm++) {
      unsigned lo = (unsigned)f2bf(st[tm][tn][0] * inv) | ((unsigned)f2bf(st[tm][tn][1] * inv) << 16);
      unsigned hi = (unsigned)f2bf(st[tm][tn][2] * inv) | ((unsigned)f2bf(st[tm][tn][3] * inv) << 16);
      uint2 pk; pk.x = lo; pk.y = hi;
      *(uint2*)&Pb[h][q][tm * 16 + g16 * 4] = pk;
    }
  }

  f32x4 oatt[4][2];
  #pragma unroll
  for (int qt = 0; qt < 4; qt++)
    #pragma unroll
    for (int dt = 0; dt < 2; dt++) oatt[qt][dt] = (f32x4){0.f, 0.f, 0.f, 0.f};
  __builtin_amdgcn_s_setprio(1);
  #pragma unroll
  for (int ks = 0; ks < 2; ks++) {
    short8 vb[2];
    #pragma unroll
    for (int dt = 0; dt < 2; dt++)
      vb[dt] = *(const short8*)&Vt[h][dt * 16 + l15][ks * 32 + g16 * 8];
    #pragma unroll
    for (int qt = 0; qt < 4; qt++) {
      short8 pa = *(const short8*)&Pb[h][qt * 16 + l15][ks * 32 + g16 * 8];
      #pragma unroll
      for (int dt = 0; dt < 2; dt++)
        oatt[qt][dt] = __builtin_amdgcn_mfma_f32_16x16x32_bf16(pa, vb[dt], oatt[qt][dt], 0, 0, 0);
    }
  }
  __builtin_amdgcn_s_setprio(0);

  bar_lds();                               // Pb/Vt reads done; O_lds overwrites Pb
  #pragma unroll
  for (int qt = 0; qt < 4; qt++)
    #pragma unroll
    for (int dt = 0; dt < 2; dt++) {
      int d = dt * 16 + l15;
      if (d < 24) {
        #pragma unroll
        for (int r = 0; r < 4; r++)
          O_lds[qt * 16 + g16 * 4 + r][h * 24 + d] = f2bf(oatt[qt][dt][r]);
      }
    }
  bar_cnt0();                              // O visible + Wo DMAs drained

  // ---- proj (swapped): lane = token, regs = 4 consecutive outcols ----
  f32x4 pacc[6];
  #pragma unroll
  for (int nt = 0; nt < 6; nt++) pacc[nt] = (f32x4){0.f, 0.f, 0.f, 0.f};
  __builtin_amdgcn_s_setprio(1);
  #pragma unroll
  for (int ks = 0; ks < 3; ks++) {
    short8 pa = *(const short8*)&O_lds[w * 16 + l15][ks * 32 + g16 * 8];
    #pragma unroll
    for (int nt = 0; nt < 6; nt++) {
      const ushort_t* buf = WsH[(nt < 3) ? 0 : 1];
      short8 wb = *reinterpret_cast<const short8*>(&buf[((nt % 3) * 16 + l15) * 96 + ks * 32 + g16 * 8]);
      pacc[nt] = __builtin_amdgcn_mfma_f32_16x16x32_bf16(wb, pa, pacc[nt], 0, 0, 0);
    }
  }
  __builtin_amdgcn_s_setprio(0);
  bar_lds();                               // all waves done reading Wo bufs
  stage_half3(stage_src(8, Wqkv, Wo, W1t, W2c), WsH[0], tid);   // W1c0h0
  stage_half3(stage_src(9, Wqkv, Wo, W1t, W2c), WsH[1], tid);   // W1c0h1

  // ---- epilogue: x2 = pacc + bo + x-residual; LN2 via 2 shfl; write h_ln/x2L ----
  size_t t = (size_t)TOK(w * 16 + l15);
  int rowoff = (w * 16 + l15);
  {
    float xv[24];
    float sm = 0.f, sq = 0.f;
    #pragma unroll
    for (int nt = 0; nt < 6; nt++) {
      int c0 = nt * 16 + g16 * 4;
      f32x4 bo4 = *reinterpret_cast<const f32x4*>(&bo[c0]);
      f32x4 xr  = *reinterpret_cast<const f32x4*>(&x[t * 96 + c0]);
      #pragma unroll
      for (int r = 0; r < 4; r++) {
        float v = pacc[nt][r] + bo4[r] + xr[r];
        xv[nt * 4 + r] = v; sm += v; sq += v * v;
      }
    }
    sm += __shfl_xor(sm, 16); sq += __shfl_xor(sq, 16);
    sm += __shfl_xor(sm, 32); sq += __shfl_xor(sq, 32);
    float mean = sm * (1.0f / 96.0f);
    float var  = sq * (1.0f / 96.0f) - mean * mean;
    float rstd = rsqrtf(var + 1e-5f);
    #pragma unroll
    for (int nt = 0; nt < 6; nt++) {
      int c0 = nt * 16 + g16 * 4;
      f32x4 g4 = *reinterpret_cast<const f32x4*>(&ln2g[c0]);
      f32x4 b4 = *reinterpret_cast<const f32x4*>(&ln2b[c0]);
      unsigned hlo, hhi, xlo, xhi;
      float h0 = (xv[nt*4+0] - mean) * rstd * g4[0] + b4[0];
      float h1 = (xv[nt*4+1] - mean) * rstd * g4[1] + b4[1];
      float h2v = (xv[nt*4+2] - mean) * rstd * g4[2] + b4[2];
      float h3 = (xv[nt*4+3] - mean) * rstd * g4[3] + b4[3];
      hlo = (unsigned)f2bf(h0) | ((unsigned)f2bf(h1) << 16);
      hhi = (unsigned)f2bf(h2v) | ((unsigned)f2bf(h3) << 16);
      xlo = (unsigned)f2bf(xv[nt*4+0]) | ((unsigned)f2bf(xv[nt*4+1]) << 16);
      xhi = (unsigned)f2bf(xv[nt*4+2]) | ((unsigned)f2bf(xv[nt*4+3]) << 16);
      uint2 ph; ph.x = hlo; ph.y = hhi;
      uint2 px; px.x = xlo; px.y = xhi;
      *reinterpret_cast<uint2*>(&h_ln[rowoff * 104 + c0]) = ph;
      *reinterpret_cast<uint2*>(&x2L[rowoff * 96 + c0]) = px;
    }
  }
  short8 hf[3];                            // own rows, in-order LDS
  #pragma unroll
  for (int ks = 0; ks < 3; ks++)
    hf[ks] = *reinterpret_cast<const short8*>(&h_ln[rowoff * 104 + ks * 32 + g16 * 8]);
  __builtin_amdgcn_sched_barrier(0);

  // ---- MLP: 16 half-slice phases (hidx 8..23) ----
  f32x4 oacc[6];
  #pragma unroll
  for (int nt = 0; nt < 6; nt++) oacc[nt] = (f32x4){0.f, 0.f, 0.f, 0.f};
  short8 mf[3];
  for (int m = 0; m < 16; ++m) {
    int cc = m >> 2, p = m & 3;
    const ushort_t* buf = WsH[m & 1];
    if (m == 15) bar_cnt0(); else bar_cnt3();
    if (p < 2) {
      // W1 half: mid cols (p*3+jj)*16.. of chunk cc
      f32x4 accM[3];
      #pragma unroll
      for (int jj = 0; jj < 3; jj++) accM[jj] = (f32x4){0.f, 0.f, 0.f, 0.f};
      __builtin_amdgcn_s_setprio(1);
      #pragma unroll
      for (int jj = 0; jj < 3; jj++)
        #pragma unroll
        for (int ks = 0; ks < 3; ks++) {
          short8 wfr = *reinterpret_cast<const short8*>(&buf[(jj * 16 + l15) * 96 + ks * 32 + g16 * 8]);
          accM[jj] = __builtin_amdgcn_mfma_f32_16x16x32_bf16(wfr, hf[ks], accM[jj], 0, 0, 0);
        }
      __builtin_amdgcn_s_setprio(0);
      bar_lds();
      if (m + 2 <= 15) stage_half3(stage_src(10 + m, Wqkv, Wo, W1t, W2c), WsH[m & 1], tid);
      #pragma unroll
      for (int jj = 0; jj < 3; jj++) {
        int lc = (p * 3 + jj) * 16 + g16 * 4;
        f32x4 bb4 = *reinterpret_cast<const f32x4*>(&b1[cc * 96 + lc]);
        float g0 = gelu_f(accM[jj][0] + bb4[0]);
        float g1 = gelu_f(accM[jj][1] + bb4[1]);
        float g2v = gelu_f(accM[jj][2] + bb4[2]);
        float g3 = gelu_f(accM[jj][3] + bb4[3]);
        unsigned lo = (unsigned)f2bf(g0) | ((unsigned)f2bf(g1) << 16);
        unsigned hi = (unsigned)f2bf(g2v) | ((unsigned)f2bf(g3) << 16);
        uint2 pk; pk.x = lo; pk.y = hi;
        *reinterpret_cast<uint2*>(&mid[rowoff * 104 + lc]) = pk;
      }
      if (p == 1) {
        #pragma unroll
        for (int ks = 0; ks < 3; ks++)
          mf[ks] = *reinterpret_cast<const short8*>(&mid[rowoff * 104 + ks * 32 + g16 * 8]);
      }
    } else {
      // W2 half: accumulate outcols (p-2)*3+jj
      int jb = (p - 2) * 3;
      __builtin_amdgcn_s_setprio(1);
      #pragma unroll
      for (int jj = 0; jj < 3; jj++)
        #pragma unroll
        for (int ks = 0; ks < 3; ks++) {
          short8 wfr = *reinterpret_cast<const short8*>(&buf[(jj * 16 + l15) * 96 + ks * 32 + g16 * 8]);
          oacc[jb + jj] = __builtin_amdgcn_mfma_f32_16x16x32_bf16(wfr, mf[ks], oacc[jb + jj], 0, 0, 0);
        }
      __builtin_amdgcn_s_setprio(0);
      if (m < 15) {
        bar_lds();
        if (m + 2 <= 15) stage_half3(stage_src(10 + m, Wqkv, Wo, W1t, W2c), WsH[m & 1], tid);
      }
    }
  }

  // ---- final epilogue: out = oacc + b2 + x2 (fp32 stores) ----
  #pragma unroll
  for (int nt = 0; nt < 6; nt++) {
    int c0 = nt * 16 + g16 * 4;
    f32x4 b24 = *reinterpret_cast<const f32x4*>(&b2[c0]);
    short4b xr2 = *reinterpret_cast<const short4b*>(&x2L[rowoff * 96 + c0]);
    f32x4 o;
    #pragma unroll
    for (int r = 0; r < 4; r++) o[r] = oacc[nt][r] + b24[r] + bf2f((ushort_t)xr2[r]);
    *reinterpret_cast<f32x4*>(&outp[t * 96 + c0]) = o;
  }
  #undef TOK
}

// ---------------- launch ----------------
extern "C" void kernel_launch(void* const* d_in, const int* in_sizes, int n_in,
                              void* d_out, int out_size, void* d_ws, size_t ws_size,
                              hipStream_t stream)
{
  (void)in_sizes; (void)n_in; (void)out_size; (void)ws_size;
  const float* x    = (const float*)d_in[0];
  const float* ln1g = (const float*)d_in[1];
  const float* ln1b = (const float*)d_in[2];
  const float* wq   = (const float*)d_in[3];
  const float* bq   = (const float*)d_in[4];
  const float* wk   = (const float*)d_in[5];
  const float* bk   = (const float*)d_in[6];
  const float* wv   = (const float*)d_in[7];
  const float* bv   = (const float*)d_in[8];
  const float* wo   = (const float*)d_in[9];
  const float* bo   = (const float*)d_in[10];
  const float* ln2g = (const float*)d_in[11];
  const float* ln2b = (const float*)d_in[12];
  const float* w1   = (const float*)d_in[13];
  const float* b1   = (const float*)d_in[14];
  const float* w2   = (const float*)d_in[15];
  const float* b2   = (const float*)d_in[16];

  char* ws = (char*)d_ws;
  ushort_t* Wqkv = (ushort_t*)(ws);                          // [288][96]  55,296 B
  ushort_t* Wo   = (ushort_t*)(ws + 55296);                  // [96][96]   18,432 B
  ushort_t* W1   = (ushort_t*)(ws + 55296 + 18432);          // [384][96]  73,728 B
  ushort_t* W2c  = (ushort_t*)(ws + 55296 + 18432 + 73728);  // [4][96][96] 73,728 B
  float*    biasq= (float*)   (ws + 55296 + 18432 + 73728 + 73728); // [288] fp32

  prep_kernel<<<434, 256, 0, stream>>>(wq, wk, wv, wo, w1, w2, bq, bk, bv,
                                       Wqkv, Wo, W1, W2c, biasq);
  fat2_kernel<<<4096, 256, 0, stream>>>(x, ln1g, ln1b, Wqkv, biasq, Wo, bo,
                                        ln2g, ln2b, W1, b1, W2c, b2, (float*)d_out);
}

// Round 20
// 182.974 us; speedup vs baseline: 1.5449x; 1.5449x over previous
//
#include <hip/hip_runtime.h>
#include <hip/hip_bf16.h>

typedef __attribute__((ext_vector_type(8))) short short8;
typedef __attribute__((ext_vector_type(4))) short short4b;
typedef __attribute__((ext_vector_type(4))) float f32x4;
typedef unsigned short ushort_t;

#define NTOK 262144   // B*D*H*W = 2*32*64*64

__device__ __forceinline__ ushort_t f2bf(float f){
  __hip_bfloat16 h = __float2bfloat16(f);
  return *reinterpret_cast<ushort_t*>(&h);
}
__device__ __forceinline__ float bf2f(ushort_t u){
  union { unsigned int i; float f; } v; v.i = ((unsigned int)u) << 16; return v.f;
}
// 1-instruction reciprocal (rel err ~2.5e-7)
__device__ __forceinline__ float fast_rcp(float x){
  float r; asm("v_rcp_f32 %0, %1" : "=v"(r) : "v"(x)); return r;
}
// sigmoid-form gelu: x * sigmoid(1.702x) (err <=0.005 for |x|<~1; our pre-act std ~0.2)
__device__ __forceinline__ float gelu_f(float x){
  float e = __expf(-1.702f * x);
  return x * fast_rcp(1.0f + e);
}
// LDS-only barrier: drains lgkm but NOT vmcnt.
__device__ __forceinline__ void bar_lds(){
  asm volatile("s_waitcnt lgkmcnt(0)" ::: "memory");
  __builtin_amdgcn_s_barrier();
  __builtin_amdgcn_sched_barrier(0);
}
// counted-vmcnt barriers (T4): leave N stage-loads in flight across the barrier
__device__ __forceinline__ void bar_cnt5(){
  asm volatile("s_waitcnt vmcnt(5) lgkmcnt(0)" ::: "memory");
  __builtin_amdgcn_s_barrier();
  __builtin_amdgcn_sched_barrier(0);
}
__device__ __forceinline__ void bar_cnt0(){
  asm volatile("s_waitcnt vmcnt(0) lgkmcnt(0)" ::: "memory");
  __builtin_amdgcn_s_barrier();
  __builtin_amdgcn_sched_barrier(0);
}
// async global->LDS, 16B per lane
__device__ __forceinline__ void gl_lds16(const ushort_t* g, ushort_t* l){
  __builtin_amdgcn_global_load_lds(
      (const __attribute__((address_space(1))) void*)g,
      (__attribute__((address_space(3))) void*)l, 16, 0, 0);
}

// fat version: [96][104] with tail-if (non-uniform count OK: fat uses __syncthreads-style drains)
template<int NT>
__device__ __forceinline__ void stage_w(const ushort_t* __restrict__ src,
                                        int src_stride, ushort_t (*dst)[104], int tid)
{
  #pragma unroll
  for (int it = 0; it < (1248 + NT - 1) / NT; ++it) {
    int u = tid + it * NT;
    if (u < 1248) {
      int row = u / 13, c16 = u % 13;
      const ushort_t* sp = src + row * src_stride + ((c16 == 12) ? 0 : c16 * 8);
      gl_lds16(sp, &dst[0][0] + (size_t)(u & ~63) * 8);
    }
  }
}

// mlp2: padded 1280-unit flat buffer (20480B), EXACTLY 5 loads/thread
__device__ __forceinline__ void stage_wp(const ushort_t* __restrict__ src,
                                         int src_stride, ushort_t* __restrict__ dst, int tid)
{
  #pragma unroll
  for (int it = 0; it < 5; ++it) {
    int u = tid + it * 256;
    int row = u / 13, c16 = u % 13;
    const ushort_t* sp = src + row * src_stride + ((c16 >= 12) ? 0 : c16 * 8);
    gl_lds16(sp, dst + (size_t)(u & ~63) * 8);
  }
}

// ---------------- weight prep: fp32 -> bf16, transposed; Q-scale folded ----------------
__global__ __launch_bounds__(256) void prep_kernel(
    const float* __restrict__ wq, const float* __restrict__ wk, const float* __restrict__ wv,
    const float* __restrict__ wo, const float* __restrict__ w1, const float* __restrict__ w2,
    const float* __restrict__ bq, const float* __restrict__ bk, const float* __restrict__ bv,
    ushort_t* __restrict__ Wqkv, ushort_t* __restrict__ Wo,
    ushort_t* __restrict__ W1, ushort_t* __restrict__ W2, float* __restrict__ biasq)
{
  const float qs = 0.20412414523193150818f;   // 1/sqrt(24)
  int i = blockIdx.x * 256 + threadIdx.x;
  if (i < 27648) {                       // Wqkv_t[j][c], j = s*96 + h*24 + d
    int j = i / 96, c = i % 96;
    int s = j / 96, rem = j % 96;
    const float* src = (s == 0) ? wq : (s == 1) ? wk : wv;
    float val = src[c * 96 + rem];
    if (s == 0) val *= qs;               // fold QK^T scale into Q
    Wqkv[j * 96 + c] = f2bf(val);
  } else if (i < 36864) {                // Wo_t[c][hd] = wo[hd][c]
    int ii = i - 27648;
    int c = ii / 96, hd = ii % 96;
    Wo[ii] = f2bf(wo[hd * 96 + c]);
  } else if (i < 73728) {                // W1_t[j][c] = w1[c][j]
    int ii = i - 36864;
    int j = ii / 96, c = ii % 96;
    W1[ii] = f2bf(w1[c * 384 + j]);
  } else if (i < 110592) {               // W2_t[c][j] = w2[j][c]
    int ii = i - 73728;
    int c = ii / 384, j = ii % 384;
    W2[ii] = f2bf(w2[j * 96 + c]);
  } else if (i < 110880) {               // combined qkv bias (fp32), Q part scaled
    int j = i - 110592;
    int s = j / 96, rem = j % 96;
    const float* src = (s == 0) ? bq : (s == 1) ? bk : bv;
    float val = src[rem];
    if (s == 0) val *= qs;
    biasq[j] = val;
  }
}

// ================= FUSED: LN1 + QKV + window attention + proj + residual =================
__global__ __launch_bounds__(256, 2) void fat_kernel(
    const float* __restrict__ x, const float* __restrict__ g, const float* __restrict__ b,
    const ushort_t* __restrict__ Wqkv, const float* __restrict__ biasq,
    const ushort_t* __restrict__ Wo, const float* __restrict__ bo,
    ushort_t* __restrict__ x2b)
{
  __shared__ ushort_t regionA[20480];      // 40,960 B: hbt[64][104] | QK[64][216]
  __shared__ ushort_t Vt[4][32][72];       // V^T[d][tok] per head (rows 24..31 junk)
  __shared__ ushort_t Ws[96][104];         // staged weight slice (Wqkv thirds, then Wo)
  ushort_t (*hbt)[104]   = reinterpret_cast<ushort_t(*)[104]>(regionA);
  ushort_t (*QK)[216]    = reinterpret_cast<ushort_t(*)[216]>(regionA + 64 * 104);
  ushort_t (*Pb)[64][72] = reinterpret_cast<ushort_t(*)[64][72]>(regionA);
  ushort_t (*O_lds)[104] = reinterpret_cast<ushort_t(*)[104]>(regionA);

  int tid = threadIdx.x;
  int bid = blockIdx.x;
  int n = (bid & 7) * 512 + (bid >> 3);    // bijective XCD swizzle (4096 % 8 == 0)
  int wq_ = n & 15, hq = (n >> 4) & 15, rest = n >> 8;
  int dq = rest & 7, bb_ = rest >> 3;
  int base = bb_ * 131072 + dq * 16384 + hq * 256 + wq_ * 4;
  #define TOK(s) (base + ((s) >> 4) * 4096 + (((s) >> 2) & 3) * 64 + ((s) & 3))

  stage_w<256>(Wqkv, 96, Ws, tid);         // group-0 weights fly under LN

  // ---- LN: thread t -> slot t>>2, quarter t&3 (24 channels) ----
  {
    int s = tid >> 2, qr = tid & 3;
    const float* xp = x + (size_t)TOK(s) * 96 + qr * 24;
    f32x4 v[6];
    float sm = 0.f, sq = 0.f;
    #pragma unroll
    for (int i = 0; i < 6; i++) {
      v[i] = *reinterpret_cast<const f32x4*>(xp + i * 4);
      #pragma unroll
      for (int j = 0; j < 4; j++) { sm += v[i][j]; sq += v[i][j] * v[i][j]; }
    }
    sm += __shfl_xor(sm, 1); sq += __shfl_xor(sq, 1);
    sm += __shfl_xor(sm, 2); sq += __shfl_xor(sq, 2);
    float mean = sm * (1.0f / 96.0f);
    float var  = sq * (1.0f / 96.0f) - mean * mean;
    float rstd = rsqrtf(var + 1e-5f);
    #pragma unroll
    for (int i8 = 0; i8 < 3; i8++) {
      short8 pk;
      #pragma unroll
      for (int j = 0; j < 8; j++) {
        int c = qr * 24 + i8 * 8 + j;
        pk[j] = (short)f2bf((v[(i8 * 8 + j) >> 2][(i8 * 8 + j) & 3] - mean) * rstd * g[c] + b[c]);
      }
      *reinterpret_cast<short8*>(&hbt[s][qr * 24 + i8 * 8]) = pk;
    }
  }
  __syncthreads();                         // LN + stage-0 visible

  int w = tid >> 6, lane = tid & 63, g16 = lane >> 4, l15 = lane & 15;
  short8 af[3];
  #pragma unroll
  for (int ks = 0; ks < 3; ks++)
    af[ks] = *reinterpret_cast<const short8*>(&hbt[w * 16 + l15][ks * 32 + g16 * 8]);

  // ---- QKV GEMM: 3 groups of 96 cols; D[outcol][token] (swapped operands) ----
  for (int grp = 0; grp < 3; ++grp) {
    f32x4 acc[6];
    #pragma unroll
    for (int j = 0; j < 6; j++) acc[j] = (f32x4){0.f, 0.f, 0.f, 0.f};
    __builtin_amdgcn_s_setprio(1);
    #pragma unroll
    for (int j = 0; j < 6; j++)
      #pragma unroll
      for (int ks = 0; ks < 3; ks++) {
        short8 wfr = *reinterpret_cast<const short8*>(&Ws[j * 16 + l15][ks * 32 + g16 * 8]);
        acc[j] = __builtin_amdgcn_mfma_f32_16x16x32_bf16(wfr, af[ks], acc[j], 0, 0, 0);
      }
    __builtin_amdgcn_s_setprio(0);
    bar_lds();                             // all waves done reading Ws
    if (grp < 2) stage_w<256>(Wqkv + (grp + 1) * 9216, 96, Ws, tid);
    else         stage_w<256>(Wo, 96, Ws, tid); // Wo flies under attention
    if (grp < 2) {
      #pragma unroll
      for (int j = 0; j < 6; j++) {
        int c0 = grp * 96 + j * 16 + g16 * 4;
        f32x4 bb4 = *reinterpret_cast<const f32x4*>(&biasq[c0]);
        unsigned lo = (unsigned)f2bf(acc[j][0] + bb4[0]) | ((unsigned)f2bf(acc[j][1] + bb4[1]) << 16);
        unsigned hi = (unsigned)f2bf(acc[j][2] + bb4[2]) | ((unsigned)f2bf(acc[j][3] + bb4[3]) << 16);
        uint2 pk; pk.x = lo; pk.y = hi;
        *reinterpret_cast<uint2*>(&QK[w * 16 + l15][c0]) = pk;
      }
    } else {
      #pragma unroll
      for (int j = 0; j < 6; j++) {
        int c0 = j * 16 + g16 * 4;
        f32x4 bb4 = *reinterpret_cast<const f32x4*>(&biasq[192 + c0]);
        #pragma unroll
        for (int r = 0; r < 4; r++) {
          int vcol = c0 + r;
          int h2 = vcol / 24, d2 = vcol - h2 * 24;
          Vt[h2][d2][w * 16 + l15] = f2bf(acc[j][r] + bb4[r]);
        }
      }
    }
    __syncthreads();                       // staged slice + epilogue writes visible
  }

  // ---- attention: wave = head ----
  int h = w;
  short8 kf[4], qf[4];
  const short8 z8 = {0, 0, 0, 0, 0, 0, 0, 0};
  #pragma unroll
  for (int i = 0; i < 4; i++) {
    qf[i] = (g16 < 3) ? *(const short8*)&QK[i * 16 + l15][h * 24 + g16 * 8]      : z8;
    kf[i] = (g16 < 3) ? *(const short8*)&QK[i * 16 + l15][96 + h * 24 + g16 * 8] : z8;
  }
  f32x4 st[4][4];
  __builtin_amdgcn_s_setprio(1);
  #pragma unroll
  for (int tm = 0; tm < 4; tm++)
    #pragma unroll
    for (int tn = 0; tn < 4; tn++)
      st[tm][tn] = __builtin_amdgcn_mfma_f32_16x16x32_bf16(kf[tm], qf[tn],
                    (f32x4){0.f, 0.f, 0.f, 0.f}, 0, 0, 0);
  __builtin_amdgcn_s_setprio(0);
  bar_lds();                               // all QK reads done (P aliases QK region)

  #pragma unroll
  for (int tn = 0; tn < 4; tn++) {
    float m = st[0][tn][0];
    #pragma unroll
    for (int tm = 0; tm < 4; tm++)
      #pragma unroll
      for (int r = 0; r < 4; r++) m = fmaxf(m, st[tm][tn][r]);
    m = fmaxf(m, __shfl_xor(m, 16));
    m = fmaxf(m, __shfl_xor(m, 32));
    float sum = 0.f;
    #pragma unroll
    for (int tm = 0; tm < 4; tm++)
      #pragma unroll
      for (int r = 0; r < 4; r++) {
        float e = __expf(st[tm][tn][r] - m);
        st[tm][tn][r] = e;
        sum += e;
      }
    sum += __shfl_xor(sum, 16);
    sum += __shfl_xor(sum, 32);
    float inv = fast_rcp(sum);
    int q = tn * 16 + l15;
    #pragma unroll
    for (int tm = 0; tm < 4; tm++) {
      unsigned lo = (unsigned)f2bf(st[tm][tn][0] * inv) | ((unsigned)f2bf(st[tm][tn][1] * inv) << 16);
      unsigned hi = (unsigned)f2bf(st[tm][tn][2] * inv) | ((unsigned)f2bf(st[tm][tn][3] * inv) << 16);
      uint2 pk; pk.x = lo; pk.y = hi;
      *(uint2*)&Pb[h][q][tm * 16 + g16 * 4] = pk;
    }
  }

  f32x4 oacc[4][2];
  #pragma unroll
  for (int qt = 0; qt < 4; qt++)
    #pragma unroll
    for (int dt = 0; dt < 2; dt++) oacc[qt][dt] = (f32x4){0.f, 0.f, 0.f, 0.f};
  __builtin_amdgcn_s_setprio(1);
  #pragma unroll
  for (int ks = 0; ks < 2; ks++) {
    short8 vb[2];
    #pragma unroll
    for (int dt = 0; dt < 2; dt++)
      vb[dt] = *(const short8*)&Vt[h][dt * 16 + l15][ks * 32 + g16 * 8];
    #pragma unroll
    for (int qt = 0; qt < 4; qt++) {
      short8 pa = *(const short8*)&Pb[h][qt * 16 + l15][ks * 32 + g16 * 8];
      #pragma unroll
      for (int dt = 0; dt < 2; dt++)
        oacc[qt][dt] = __builtin_amdgcn_mfma_f32_16x16x32_bf16(pa, vb[dt], oacc[qt][dt], 0, 0, 0);
    }
  }
  __builtin_amdgcn_s_setprio(0);

  __syncthreads();                         // everyone done with Pb/Vt; Wo DMA drained
  #pragma unroll
  for (int qt = 0; qt < 4; qt++)
    #pragma unroll
    for (int dt = 0; dt < 2; dt++) {
      int d = dt * 16 + l15;
      if (d < 24) {
        #pragma unroll
        for (int r = 0; r < 4; r++)
          O_lds[qt * 16 + g16 * 4 + r][h * 24 + d] = f2bf(oacc[qt][dt][r]);
      }
    }
  __syncthreads();

  // ---- proj (SWAPPED operands): lane = token, regs = 4 consecutive outcols ----
  f32x4 pacc[6];
  #pragma unroll
  for (int nt = 0; nt < 6; nt++) pacc[nt] = (f32x4){0.f, 0.f, 0.f, 0.f};
  __builtin_amdgcn_s_setprio(1);
  #pragma unroll
  for (int ks = 0; ks < 3; ks++) {
    short8 pa = *(const short8*)&O_lds[w * 16 + l15][ks * 32 + g16 * 8];
    #pragma unroll
    for (int nt = 0; nt < 6; nt++) {
      short8 wb = *reinterpret_cast<const short8*>(&Ws[nt * 16 + l15][ks * 32 + g16 * 8]);
      pacc[nt] = __builtin_amdgcn_mfma_f32_16x16x32_bf16(wb, pa, pacc[nt], 0, 0, 0);
    }
  }
  __builtin_amdgcn_s_setprio(0);
  {
    size_t t = (size_t)TOK(w * 16 + l15);
    #pragma unroll
    for (int nt = 0; nt < 6; nt++) {
      int c0 = nt * 16 + g16 * 4;
      f32x4 bo4 = *reinterpret_cast<const f32x4*>(&bo[c0]);
      f32x4 xr  = *reinterpret_cast<const f32x4*>(&x[t * 96 + c0]);
      float v0 = pacc[nt][0] + bo4[0] + xr[0];
      float v1 = pacc[nt][1] + bo4[1] + xr[1];
      float v2 = pacc[nt][2] + bo4[2] + xr[2];
      float v3 = pacc[nt][3] + bo4[3] + xr[3];
      unsigned lo = (unsigned)f2bf(v0) | ((unsigned)f2bf(v1) << 16);
      unsigned hi = (unsigned)f2bf(v2) | ((unsigned)f2bf(v3) << 16);
      uint2 pk; pk.x = lo; pk.y = hi;
      *reinterpret_cast<uint2*>(&x2b[t * 96 + c0]) = pk;
    }
  }
  #undef TOK
}

// ---- per-thread half-row LN (bf16 input) into LDS tile smem[128][104] ----
__device__ __forceinline__ void ln_to_lds_b(const ushort_t* __restrict__ xrow_base,
    const float* __restrict__ gg, const float* __restrict__ bb,
    ushort_t (*hbt)[104], int tid)
{
  int row = tid >> 1, half = tid & 1;
  const ushort_t* xp = xrow_base + (size_t)row * 96 + half * 48;
  short8 vv[6];
  #pragma unroll
  for (int i = 0; i < 6; i++) vv[i] = *reinterpret_cast<const short8*>(xp + i * 8);
  float v[48];
  float s = 0.f, sq = 0.f;
  #pragma unroll
  for (int i = 0; i < 6; i++)
    #pragma unroll
    for (int j = 0; j < 8; j++) {
      float f = bf2f((ushort_t)vv[i][j]);
      v[i * 8 + j] = f; s += f; sq += f * f;
    }
  s  += __shfl_xor(s, 1);
  sq += __shfl_xor(sq, 1);
  float mean = s * (1.0f / 96.0f);
  float var  = sq * (1.0f / 96.0f) - mean * mean;
  float rstd = rsqrtf(var + 1e-5f);
  #pragma unroll
  for (int i8 = 0; i8 < 6; i8++) {
    short8 pk;
    #pragma unroll
    for (int j = 0; j < 8; j++) {
      int c = half * 48 + i8 * 8 + j;
      pk[j] = (short)f2bf((v[i8 * 8 + j] - mean) * rstd * gg[c] + bb[c]);
    }
    *reinterpret_cast<short8*>(&hbt[row][half * 48 + i8 * 8]) = pk;
  }
}

// ---------------- fused LN2 + MLP + residual: counted-vmcnt ping-pong (r16 winner) ----------------
__global__ __launch_bounds__(256, 2) void mlp2_kernel(
    const ushort_t* __restrict__ x2b, const float* __restrict__ g, const float* __restrict__ b,
    const ushort_t* __restrict__ W1t, const float* __restrict__ b1,
    const ushort_t* __restrict__ W2t, const float* __restrict__ b2,
    float* __restrict__ out)
{
  __shared__ ushort_t smem[128][104];   // LN rows, then mid (same storage) 26,624 B
  __shared__ ushort_t WsA[10240];       // W1 slice, padded to 1280 units (20,480 B)
  __shared__ ushort_t WsB[10240];       // W2 slice, padded (20,480 B)
  __shared__ float bias1[384];
  __shared__ float bias2[96];
  int tid = threadIdx.x;
  int bid = blockIdx.x;
  int blk = (bid & 7) * 256 + (bid >> 3);   // bijective XCD swizzle (2048 % 8 == 0)
  size_t r0 = (size_t)blk * 128;

  stage_wp(W1t, 96, WsA, tid);          // W1[0] -> A
  stage_wp(W2t, 384, WsB, tid);         // W2[0] -> B
  bias1[tid] = b1[tid];
  if (tid < 128) bias1[256 + tid] = b1[256 + tid];
  if (tid < 96)  bias2[tid] = b2[tid];
  ln_to_lds_b(x2b + r0 * 96, g, b, smem, tid);

  int w = tid >> 6, lane = tid & 63, g16 = lane >> 4, l15 = lane & 15;
  short8 af[2][3];
  #pragma unroll
  for (int mi = 0; mi < 2; mi++)
    #pragma unroll
    for (int ks = 0; ks < 3; ks++)
      af[mi][ks] = *reinterpret_cast<const short8*>(&smem[w * 32 + mi * 16 + l15][ks * 32 + g16 * 8]);
  __builtin_amdgcn_sched_barrier(0);

  f32x4 oacc[6][2];
  #pragma unroll
  for (int nt = 0; nt < 6; nt++) { oacc[nt][0] = (f32x4){0.f,0.f,0.f,0.f}; oacc[nt][1] = (f32x4){0.f,0.f,0.f,0.f}; }

  for (int cc = 0; cc < 4; ++cc) {
    bar_cnt5();                         // A = W1[cc] resident (B's 5 still in flight)
    f32x4 acc[6][2];
    #pragma unroll
    for (int nt = 0; nt < 6; nt++) { acc[nt][0] = (f32x4){0.f,0.f,0.f,0.f}; acc[nt][1] = (f32x4){0.f,0.f,0.f,0.f}; }
    __builtin_amdgcn_s_setprio(1);
    #pragma unroll
    for (int nt = 0; nt < 6; nt++)
      #pragma unroll
      for (int ks = 0; ks < 3; ks++) {
        short8 wfr = *reinterpret_cast<const short8*>(&WsA[(nt * 16 + l15) * 104 + ks * 32 + g16 * 8]);
        acc[nt][0] = __builtin_amdgcn_mfma_f32_16x16x32_bf16(wfr, af[0][ks], acc[nt][0], 0, 0, 0);
        acc[nt][1] = __builtin_amdgcn_mfma_f32_16x16x32_bf16(wfr, af[1][ks], acc[nt][1], 0, 0, 0);
      }
    __builtin_amdgcn_s_setprio(0);
    #pragma unroll
    for (int nt = 0; nt < 6; nt++) {
      f32x4 bb4 = *reinterpret_cast<const f32x4*>(&bias1[cc * 96 + nt * 16 + g16 * 4]);
      #pragma unroll
      for (int mi = 0; mi < 2; mi++) {
        float g0 = gelu_f(acc[nt][mi][0] + bb4[0]);
        float g1 = gelu_f(acc[nt][mi][1] + bb4[1]);
        float g2 = gelu_f(acc[nt][mi][2] + bb4[2]);
        float g3 = gelu_f(acc[nt][mi][3] + bb4[3]);
        unsigned lo = (unsigned)f2bf(g0) | ((unsigned)f2bf(g1) << 16);
        unsigned hi = (unsigned)f2bf(g2) | ((unsigned)f2bf(g3) << 16);
        uint2 pk; pk.x = lo; pk.y = hi;
        *reinterpret_cast<uint2*>(&smem[w * 32 + mi * 16 + l15][nt * 16 + g16 * 4]) = pk;
      }
    }
    short8 a2[2][3];
    #pragma unroll
    for (int mi = 0; mi < 2; mi++)
      #pragma unroll
      for (int ks = 0; ks < 3; ks++)
        a2[mi][ks] = *reinterpret_cast<const short8*>(&smem[w * 32 + mi * 16 + l15][ks * 32 + g16 * 8]);
    bar_lds();                          // all waves done reading A
    if (cc < 3) stage_wp(W1t + (cc + 1) * 9216, 96, WsA, tid);   // W1[cc+1] -> A
    if (cc < 3) bar_cnt5(); else bar_cnt0();   // B = W2[cc] resident (A' in flight)
    __builtin_amdgcn_s_setprio(1);
    #pragma unroll
    for (int nt = 0; nt < 6; nt++)
      #pragma unroll
      for (int ks = 0; ks < 3; ks++) {
        short8 wfr = *reinterpret_cast<const short8*>(&WsB[(nt * 16 + l15) * 104 + ks * 32 + g16 * 8]);
        oacc[nt][0] = __builtin_amdgcn_mfma_f32_16x16x32_bf16(wfr, a2[0][ks], oacc[nt][0], 0, 0, 0);
        oacc[nt][1] = __builtin_amdgcn_mfma_f32_16x16x32_bf16(wfr, a2[1][ks], oacc[nt][1], 0, 0, 0);
      }
    __builtin_amdgcn_s_setprio(0);
    if (cc < 3) {
      bar_lds();                        // all waves done reading B
      stage_wp(W2t + (cc + 1) * 96, 384, WsB, tid);              // W2[cc+1] -> B
    }
  }

  // epilogue: out = oacc + b2 + residual(x2b) (fp32 out)
  #pragma unroll
  for (int nt = 0; nt < 6; nt++) {
    int c0 = nt * 16 + g16 * 4;
    f32x4 bb4 = *reinterpret_cast<const f32x4*>(&bias2[c0]);
    #pragma unroll
    for (int mi = 0; mi < 2; mi++) {
      size_t row = r0 + w * 32 + mi * 16 + l15;
      short4b rr = *reinterpret_cast<const short4b*>(&x2b[row * 96 + c0]);
      f32x4 o;
      #pragma unroll
      for (int r = 0; r < 4; r++) o[r] = oacc[nt][mi][r] + bb4[r] + bf2f((ushort_t)rr[r]);
      *reinterpret_cast<f32x4*>(&out[row * 96 + c0]) = o;
    }
  }
}

// ---------------- launch ----------------
extern "C" void kernel_launch(void* const* d_in, const int* in_sizes, int n_in,
                              void* d_out, int out_size, void* d_ws, size_t ws_size,
                              hipStream_t stream)
{
  (void)in_sizes; (void)n_in; (void)out_size; (void)ws_size;
  const float* x    = (const float*)d_in[0];
  const float* ln1g = (const float*)d_in[1];
  const float* ln1b = (const float*)d_in[2];
  const float* wq   = (const float*)d_in[3];
  const float* bq   = (const float*)d_in[4];
  const float* wk   = (const float*)d_in[5];
  const float* bk   = (const float*)d_in[6];
  const float* wv   = (const float*)d_in[7];
  const float* bv   = (const float*)d_in[8];
  const float* wo   = (const float*)d_in[9];
  const float* bo   = (const float*)d_in[10];
  const float* ln2g = (const float*)d_in[11];
  const float* ln2b = (const float*)d_in[12];
  const float* w1   = (const float*)d_in[13];
  const float* b1   = (const float*)d_in[14];
  const float* w2   = (const float*)d_in[15];
  const float* b2   = (const float*)d_in[16];

  char* ws = (char*)d_ws;
  ushort_t* x2b  = (ushort_t*)(ws);                          // [N,96] bf16  50,331,648 B
  char* wsw      = ws + 50331648;
  ushort_t* Wqkv = (ushort_t*)(wsw);                         // [288][96]
  ushort_t* Wo   = (ushort_t*)(wsw + 55296);                 // [96][96]
  ushort_t* W1   = (ushort_t*)(wsw + 55296 + 18432);         // [384][96]
  ushort_t* W2   = (ushort_t*)(wsw + 55296 + 18432 + 73728); // [96][384]
  float*    biasq= (float*)   (wsw + 55296 + 18432 + 73728 + 73728); // [288] fp32

  prep_kernel<<<434, 256, 0, stream>>>(wq, wk, wv, wo, w1, w2, bq, bk, bv,
                                       Wqkv, Wo, W1, W2, biasq);
  fat_kernel<<<4096, 256, 0, stream>>>(x, ln1g, ln1b, Wqkv, biasq, Wo, bo, x2b);
  mlp2_kernel<<<NTOK / 128, 256, 0, stream>>>(x2b, ln2g, ln2b, W1, b1, W2, b2, (float*)d_out);
}